// Round 2
// baseline (129.154 us; speedup 1.0000x reference)
//
#include <hip/hip_runtime.h>

// Self-attention (SAGAN-style), B=16, C=64, H=W=64. d8=8, d2=32, N=4096, M=1024.
// Round 9b: scores moved to v_mfma_f32_16x16x16_f16 (K=16, 2x pad instead of
// 4x pad at K=32 bf16) -- same C/D layout, so the S^T->PV register remap and
// gTp permutation are unchanged. theta pre-scaled by log2(e) at pack time so
// attn uses exp2f (bare v_exp_f32, no v_mul). theta/phi stored as f16
// (better mantissa than bf16); phi k-pad shrinks 32->16 cols. g/PV path
// (bf16 16x16x32) and epilogue identical to round 8.
// (9b: fix cvt_pkrtz return-type mismatch via decltype bitcast.)

#define B_   16
#define C_   64
#define HW_  4096
#define M_   1024

typedef __attribute__((ext_vector_type(8))) short bf16x8;
typedef __attribute__((ext_vector_type(4))) float f32x4;
typedef __attribute__((ext_vector_type(4))) _Float16 f16x4;

#define LOG2E 1.44269504088896340736f

__device__ __forceinline__ unsigned short f2bf(float f) {   // RNE
    union { float f; unsigned int u; } v; v.f = f;
    return (unsigned short)((v.u + 0x7FFFu + ((v.u >> 16) & 1u)) >> 16);
}
__device__ __forceinline__ unsigned int packh2(float a, float b) {  // f16 pair (RTZ)
    auto h = __builtin_amdgcn_cvt_pkrtz(a, b);      // __fp16 ext_vector(2)
    union { decltype(h) h; unsigned int u; } v;
    v.h = h;
    return v.u;
}
__device__ __forceinline__ unsigned int pack2t(float a, float b) {  // trunc bf16 pair
    union { float f; unsigned int u; } ua, ub; ua.f = a; ub.f = b;
    return (ua.u >> 16) | (ub.u & 0xFFFF0000u);
}

// ---------------------------------------------------------------------------
// proj: thetaH(B,N,8) f16, pre-scaled by log2(e); phiH(B,1024,16) f16 with
// cols 8..15 = 0; gTp(B,32,1024) bf16 with m permuted per 32-block:
// ms=m&31, p = (m&~31) + ((ms>>2)&3)*8 + (ms>>4)*4 + (ms&3).
// ---------------------------------------------------------------------------
__global__ __launch_bounds__(256) void proj_kernel(
    const float* __restrict__ x,
    const float* __restrict__ w_theta, const float* __restrict__ b_theta,
    const float* __restrict__ w_phi,   const float* __restrict__ b_phi,
    const float* __restrict__ w_g,     const float* __restrict__ b_g,
    unsigned short* __restrict__ thetaH,
    unsigned short* __restrict__ phiH,
    unsigned short* __restrict__ gTp)
{
    __shared__ __align__(16) float x_l[64 * 132];   // [c][px] stride 132
    __shared__ float pool_l[128][41];               // 0..7 phi, 8..39 g

    const int tid = threadIdx.x;
    const int b   = blockIdx.y;
    const int rp  = blockIdx.x;          // row pair 0..31
    const int n0  = rp * 128;

    // stage x tile: 64 ch x 128 px, coalesced float4
    {
        const float4* src = (const float4*)(x + (size_t)b * C_ * HW_ + n0);
        #pragma unroll
        for (int j = 0; j < 8; j++) {
            int idx = tid + j * 256;
            int c = idx >> 5, p4 = idx & 31;
            float4 v = src[(size_t)c * (HW_ / 4) + p4];
            *(float4*)&x_l[c * 132 + p4 * 4] = v;
        }
    }
    __syncthreads();

    const int px = tid & 127;
    const int og = tid >> 7;             // wave-uniform half

    if (og == 0) {
        float th[8], ph[8], g0[8];
        #pragma unroll
        for (int o = 0; o < 8; o++) { th[o] = b_theta[o]; ph[o] = b_phi[o]; g0[o] = b_g[o]; }
        #pragma unroll 4
        for (int c = 0; c < C_; c++) {
            float xv = x_l[c * 132 + px];
            #pragma unroll
            for (int o = 0; o < 8; o++) th[o] += xv * w_theta[o * 64 + c];
            #pragma unroll
            for (int o = 0; o < 8; o++) ph[o] += xv * w_phi[o * 64 + c];
            #pragma unroll
            for (int o = 0; o < 8; o++) g0[o] += xv * w_g[o * 64 + c];
        }
        // theta: f16, pre-scaled by log2(e) so attn can use exp2 directly
        unsigned short* tout = thetaH + ((size_t)b * HW_ + n0 + px) * 8;
        uint4 tv;
        tv.x = packh2(th[0] * LOG2E, th[1] * LOG2E);
        tv.y = packh2(th[2] * LOG2E, th[3] * LOG2E);
        tv.z = packh2(th[4] * LOG2E, th[5] * LOG2E);
        tv.w = packh2(th[6] * LOG2E, th[7] * LOG2E);
        *(uint4*)tout = tv;
        #pragma unroll
        for (int o = 0; o < 8; o++) { pool_l[px][o] = ph[o]; pool_l[px][8 + o] = g0[o]; }
    } else {
        float gg[24];
        #pragma unroll
        for (int o = 0; o < 24; o++) gg[o] = b_g[8 + o];
        #pragma unroll 4
        for (int c = 0; c < C_; c++) {
            float xv = x_l[c * 132 + px];
            #pragma unroll
            for (int o = 0; o < 24; o++) gg[o] += xv * w_g[(8 + o) * 64 + c];
        }
        #pragma unroll
        for (int o = 0; o < 24; o++) pool_l[px][16 + o] = gg[o];
    }
    __syncthreads();

    // parallel 2x2 max-pool over all 256 threads:
    // j = pooled col (0..31), grp = tid>>5 (0..7) handles channels grp*5..grp*5+4
    {
        const int j   = tid & 31;
        const int grp = tid >> 5;
        const int p00 = 2 * j, p01 = 2 * j + 1, p10 = 64 + 2 * j, p11 = 65 + 2 * j;
        const int mq   = rp * 32 + j;
        const int pcol = rp * 32 + ((j >> 2) & 3) * 8 + (j >> 4) * 4 + (j & 3);
        #pragma unroll
        for (int k = 0; k < 5; k++) {
            const int ch = grp * 5 + k;          // 0..39 exactly
            float v = fmaxf(fmaxf(pool_l[p00][ch], pool_l[p01][ch]),
                            fmaxf(pool_l[p10][ch], pool_l[p11][ch]));
            if (ch < 8)
                ((_Float16*)phiH)[((size_t)b * M_ + mq) * 16 + ch] = (_Float16)v;
            else
                gTp[((size_t)b * 32 + (ch - 8)) * M_ + pcol] = f2bf(v);
        }
        // zero phi k-pads (cols 8..15): 32 m x 1 uint4
        if (tid < 32) {
            *(uint4*)((_Float16*)phiH + ((size_t)b * M_ + rp * 32 + tid) * 16 + 8) =
                make_uint4(0, 0, 0, 0);
        }
    }
}

// ---------------------------------------------------------------------------
// attn: block = (batch, 64-q tile), 256 thr = 4 waves. Wave wv privately owns
// m-chunks wv*4..wv*4+3; per chunk: phi/g global loads (reused over 4
// q-tiles), 16 score (16x16x16 f16) + 16 PV (16x16x32 bf16) MFMAs, 64 exp2.
// Score C/D layout identical to the old K=32 version, so the register P remap
// (S^T C-layout == PV B-frag with k=quad*8+j <-> m = s*32+(j>>2)*16+quad*4+(j&3))
// is unchanged. Partial O^T / rowsum per wave; cross-wave reduce in epilogue.
// ---------------------------------------------------------------------------
__global__ __launch_bounds__(256, 4) void attn_kernel(
    const float* __restrict__ x,
    const unsigned short* __restrict__ thetaH,   // [b][n][8] f16, *log2e
    const unsigned short* __restrict__ phiH,     // [b][m][16] f16, cols 8..15 = 0
    const unsigned short* __restrict__ gTp,      // [b][c][1024] bf16, m-permuted
    const float* __restrict__ w_o, const float* __restrict__ b_o,
    const float* __restrict__ sigma,
    float* __restrict__ out)
{
    __shared__ float Op_l[4][64 * 33];   // [wv][q][c] partial O
    __shared__ float rs_l[4][64];        // [wv][q] partial rowsums

    const int tid   = threadIdx.x;
    const int b     = blockIdx.y;
    const int qbase = blockIdx.x * 64;
    const int wv    = tid >> 6;
    const int lane  = tid & 63;
    const int ln15  = lane & 15;
    const int quad  = lane >> 4;

    const _Float16* phiP = (const _Float16*)phiH + (size_t)b * M_ * 16;
    const unsigned short* gP = gTp + (size_t)b * 32 * M_;

    // theta B-frags for the 4 q-tiles (loaded once; k = quad*4+j, quads 0-1 real)
    f16x4 th[4];
    {
        const f16x4 z = {0, 0, 0, 0};
        #pragma unroll
        for (int qt = 0; qt < 4; qt++) {
            const _Float16* tp = (const _Float16*)thetaH
                + ((size_t)b * HW_ + qbase + qt * 16 + ln15) * 8 + (quad & 1) * 4;
            f16x4 t = *(const f16x4*)tp;
            th[qt] = (quad < 2) ? t : z;
        }
    }

    #define LD_PHI(ch_, mt_) \
        (*(const f16x4*)(phiP + ((ch_) * 64 + (mt_) * 16 + ln15) * 16 + quad * 4))
    #define LD_G(ch_, h_, s_) \
        (*(const bf16x8*)(gP + (size_t)((h_) * 16 + ln15) * M_ + (ch_) * 64 + (s_) * 32 + quad * 8))

    f32x4 acc[2][4];                     // [c-half][q-tile], O^T partial
    #pragma unroll
    for (int h = 0; h < 2; h++)
        #pragma unroll
        for (int qt = 0; qt < 4; qt++) acc[h][qt] = (f32x4){0.f, 0.f, 0.f, 0.f};
    float rs_p[4] = {0.f, 0.f, 0.f, 0.f};

    #pragma unroll
    for (int wc = 0; wc < 4; wc++) {
        const int ch = wv * 4 + wc;
        f16x4 pf[4];
        #pragma unroll
        for (int mt = 0; mt < 4; mt++) pf[mt] = LD_PHI(ch, mt);
        bf16x8 gf[2][2];
        gf[0][0] = LD_G(ch, 0, 0); gf[0][1] = LD_G(ch, 0, 1);
        gf[1][0] = LD_G(ch, 1, 0); gf[1][1] = LD_G(ch, 1, 1);

        #pragma unroll
        for (int s = 0; s < 2; s++) {
            #pragma unroll
            for (int qt = 0; qt < 4; qt++) {
                const f32x4 zc = {0.f, 0.f, 0.f, 0.f};
                f32x4 S0 = __builtin_amdgcn_mfma_f32_16x16x16f16(pf[2 * s],     th[qt], zc, 0, 0, 0);
                f32x4 S1 = __builtin_amdgcn_mfma_f32_16x16x16f16(pf[2 * s + 1], th[qt], zc, 0, 0, 0);
                float e0[4], e1[4];
                #pragma unroll
                for (int r = 0; r < 4; r++) {
                    e0[r] = exp2f(S0[r]);        // theta pre-scaled by log2e
                    e1[r] = exp2f(S1[r]);
                    rs_p[qt] += e0[r] + e1[r];
                }
                union { bf16x8 v; unsigned int u[4]; } pb;
                pb.u[0] = pack2t(e0[0], e0[1]); pb.u[1] = pack2t(e0[2], e0[3]);
                pb.u[2] = pack2t(e1[0], e1[1]); pb.u[3] = pack2t(e1[2], e1[3]);
                acc[0][qt] = __builtin_amdgcn_mfma_f32_16x16x32_bf16(gf[0][s], pb.v, acc[0][qt], 0, 0, 0);
                acc[1][qt] = __builtin_amdgcn_mfma_f32_16x16x32_bf16(gf[1][s], pb.v, acc[1][qt], 0, 0, 0);
            }
        }
    }
    #undef LD_PHI
    #undef LD_G

    // rowsum partials: reduce over quads (m-rows) within the wave
    {
        float v[4];
        #pragma unroll
        for (int qt = 0; qt < 4; qt++) {
            float t = rs_p[qt];
            t += __shfl_xor(t, 16);
            t += __shfl_xor(t, 32);
            v[qt] = t;
        }
        if (quad == 0) {
            #pragma unroll
            for (int qt = 0; qt < 4; qt++) rs_l[wv][qt * 16 + ln15] = v[qt];
        }
    }
    // O^T partials -> LDS: lane owns col q=qt*16+ln15, rows c=h*16+quad*4+r
    #pragma unroll
    for (int h = 0; h < 2; h++)
        #pragma unroll
        for (int qt = 0; qt < 4; qt++)
            #pragma unroll
            for (int r = 0; r < 4; r++)
                Op_l[wv][(qt * 16 + ln15) * 33 + h * 16 + quad * 4 + r] = acc[h][qt][r];
    __syncthreads();

    // epilogue: cross-wave reduce + normalize + w_o conv + bias + residual
    const int q = tid & 63;
    const float rowsum = rs_l[0][q] + rs_l[1][q] + rs_l[2][q] + rs_l[3][q];
    const float sg  = sigma[0];
    const float inv = sg / rowsum;
    float o[32];
    #pragma unroll
    for (int c = 0; c < 32; c++)
        o[c] = Op_l[0][q * 33 + c] + Op_l[1][q * 33 + c]
             + Op_l[2][q * 33 + c] + Op_l[3][q * 33 + c];
    const size_t xb = (size_t)b * C_ * HW_ + qbase + q;
    #pragma unroll
    for (int k = 0; k < 16; k++) {
        const int co = wv * 16 + k;
        float t = 0.f;
        #pragma unroll
        for (int c = 0; c < 32; c++) t += w_o[co * 32 + c] * o[c];
        out[xb + (size_t)co * HW_] = x[xb + (size_t)co * HW_] + t * inv + sg * b_o[co];
    }
}

// ---------------------------------------------------------------------------
extern "C" void kernel_launch(void* const* d_in, const int* in_sizes, int n_in,
                              void* d_out, int out_size, void* d_ws, size_t ws_size,
                              hipStream_t stream)
{
    const float* x       = (const float*)d_in[0];
    const float* w_theta = (const float*)d_in[1];
    const float* b_theta = (const float*)d_in[2];
    const float* w_phi   = (const float*)d_in[3];
    const float* b_phi   = (const float*)d_in[4];
    const float* w_g     = (const float*)d_in[5];
    const float* b_g     = (const float*)d_in[6];
    const float* w_o     = (const float*)d_in[7];
    const float* b_o     = (const float*)d_in[8];
    const float* sigma   = (const float*)d_in[9];
    float* out = (float*)d_out;

    // workspace: thetaH 1 MB (f16), phiH 0.5 MB (f16), gTp 1 MB (bf16)
    unsigned short* thetaH = (unsigned short*)d_ws;
    unsigned short* phiH   = thetaH + (size_t)B_ * HW_ * 8;
    unsigned short* gTp    = phiH   + (size_t)B_ * M_ * 16;

    proj_kernel<<<dim3(32, B_), 256, 0, stream>>>(
        x, w_theta, b_theta, w_phi, b_phi, w_g, b_g, thetaH, phiH, gTp);
    attn_kernel<<<dim3(64, B_), 256, 0, stream>>>(
        x, thetaH, phiH, gTp, w_o, b_o, sigma, out);
}